// Round 2
// baseline (752.708 us; speedup 1.0000x reference)
//
#include <hip/hip_runtime.h>

// CubicSplineUpsampling: (2,3,96,96,96) f32 -> (2,3,192,192,192) f32.
//
// Fused formulation: per axis, out_line(192) = M * in_line(96), where
// M = U_clamped(192x96) . W(96x96); W = exact recursive cubic-spline prefilter
// matrix (built in fp64 on device), U = 2x cubic upsampler with edge clamp.
// M is banded: 28 taps centered at j0 = (i>>1)-13 (truncation ~1e-6).
//
// Pass Z: thread-per-output, taps via explicit arrays (full MLP, L1-hot).
// Pass Y/X: line-in-registers (96 VGPRs), coalesced loads/stores, scalar weights.

#define TAPS 28

__device__ double g_Wd[96 * 96];
__device__ float g_Mb[192 * TAPS];   // [i][t]   row-major, wave-uniform reads
__device__ float g_MbT[TAPS * 192];  // [t][i]   for lane-varying i (pass Z)
__device__ float g_bufA[6 * 96 * 96 * 192];   // after Z pass
__device__ float g_bufB[6 * 96 * 192 * 192];  // after Y pass

__global__ void compute_Wd_kernel(double* __restrict__ Wd) {
    int j = threadIdx.x;
    if (j >= 96) return;
    const double p = -0.26794919243112270647253365849413;  // sqrt(3)-2
    double c[96];
    double pj = 1.0;
    for (int t = 0; t < j; ++t) pj *= p;
    double p191j = 1.0;
    for (int t = 0; t < 191 - j; ++t) p191j *= p;
    double p2n = 1.0;
    for (int t = 0; t < 192; ++t) p2n *= p;
    double K = p / (1.0 - p2n);
    double cur = 6.0 * K * (pj + p191j) + (j == 0 ? 6.0 : 0.0);
    c[0] = cur;
    for (int i = 1; i < 96; ++i) {
        cur = (i == j ? 6.0 : 0.0) + p * cur;
        c[i] = cur;
    }
    double nxt = cur * (p / (p - 1.0));
    Wd[95 * 96 + j] = nxt;
    for (int i = 94; i >= 0; --i) {
        nxt = p * (nxt - c[i]);
        Wd[i * 96 + j] = nxt;
    }
}

__global__ void compute_M_kernel(const double* __restrict__ Wd,
                                 float* __restrict__ Mb,
                                 float* __restrict__ MbT) {
    int i = threadIdx.x;
    if (i >= 192) return;
    const double cw[8] = {1.0 / 384.0, 121.0 / 384.0, 235.0 / 384.0, 27.0 / 384.0,
                          27.0 / 384.0, 235.0 / 384.0, 121.0 / 384.0, 1.0 / 384.0};
    int ph = i & 1;
    int c = i >> 1;
    for (int t = 0; t < TAPS; ++t) {
        int j = c - 13 + t;
        double m = 0.0;
        if (j >= 0 && j < 96) {
            for (int tt = 0; tt < 4; ++tt) {
                int k = c + ph - 2 + tt;
                k = k < 0 ? 0 : (k > 95 ? 95 : k);
                m += cw[ph * 4 + tt] * Wd[k * 96 + j];
            }
        }
        Mb[i * TAPS + t] = (float)m;
        MbT[t * 192 + i] = (float)m;
    }
}

// Z pass: in (6,96,96,96) -> out (6,96,96,192). Thread per output element.
__global__ __launch_bounds__(256) void pass_z(const float* __restrict__ in,
                                              float* __restrict__ out,
                                              const float* __restrict__ MbT) {
    int idx = blockIdx.x * 256 + threadIdx.x;
    int i = idx % 192;
    int line = idx / 192;
    const float* src = in + (size_t)line * 96;
    int c = i >> 1;
    float w[TAPS], xv[TAPS];
#pragma unroll
    for (int t = 0; t < TAPS; ++t) w[t] = MbT[t * 192 + i];
#pragma unroll
    for (int t = 0; t < TAPS; ++t) {
        int j = c - 13 + t;
        j = j < 0 ? 0 : (j > 95 ? 95 : j);
        xv[t] = src[j];
    }
    float s = 0.0f;
#pragma unroll
    for (int t = 0; t < TAPS; ++t) s += w[t] * xv[t];
    out[idx] = s;
}

// Line pass along axis with element stride INNER. in [O][96][INNER] -> out [O][192][INNER].
// One thread per (o, r): holds the whole 96-line in registers; all global access coalesced.
template <int INNER>
__global__ __launch_bounds__(256, 2) void pass_line(const float* __restrict__ in,
                                                    float* __restrict__ out,
                                                    const float* __restrict__ Mb) {
    int idx = blockIdx.x * 256 + threadIdx.x;
    int r = idx % INNER;
    int o = idx / INNER;
    const float* src = in + (size_t)o * 96 * INNER + r;
    float* dst = out + (size_t)o * 192 * INNER + r;
    float x[96];
#pragma unroll
    for (int j = 0; j < 96; ++j) x[j] = src[(size_t)j * INNER];
#pragma unroll
    for (int m = 0; m < 96; ++m) {
        const float* w0 = Mb + (2 * m) * TAPS;
        const float* w1 = w0 + TAPS;
        float a0 = 0.0f, a1 = 0.0f;
#pragma unroll
        for (int t = 0; t < TAPS; ++t) {
            int j = m - 13 + t;
            j = j < 0 ? 0 : (j > 95 ? 95 : j);
            float xv = x[j];
            a0 += w0[t] * xv;
            a1 += w1[t] * xv;
        }
        dst[(size_t)(2 * m) * INNER] = a0;
        dst[(size_t)(2 * m + 1) * INNER] = a1;
    }
}

extern "C" void kernel_launch(void* const* d_in, const int* in_sizes, int n_in,
                              void* d_out, int out_size, void* d_ws, size_t ws_size,
                              hipStream_t stream) {
    const float* x = (const float*)d_in[0];
    float* out = (float*)d_out;
    double* Wd;
    float *Mb, *MbT, *bufA, *bufB;
    hipGetSymbolAddress((void**)&Wd, HIP_SYMBOL(g_Wd));
    hipGetSymbolAddress((void**)&Mb, HIP_SYMBOL(g_Mb));
    hipGetSymbolAddress((void**)&MbT, HIP_SYMBOL(g_MbT));
    hipGetSymbolAddress((void**)&bufA, HIP_SYMBOL(g_bufA));
    hipGetSymbolAddress((void**)&bufB, HIP_SYMBOL(g_bufB));

    compute_Wd_kernel<<<1, 96, 0, stream>>>(Wd);
    compute_M_kernel<<<1, 192, 0, stream>>>(Wd, Mb, MbT);

    // Z: (6,96,96,96) -> (6,96,96,192): 10,616,832 outputs = 41472 * 256
    pass_z<<<41472, 256, 0, stream>>>(x, bufA, MbT);
    // Y: [O=6*96][96][192] -> [O][192][192]: 110,592 lines = 432 * 256 threads
    pass_line<192><<<432, 256, 0, stream>>>(bufA, bufB, Mb);
    // X: [O=6][96][36864] -> [O][192][36864]: 221,184 lines = 864 * 256 threads
    pass_line<36864><<<864, 256, 0, stream>>>(bufB, out, Mb);
}

// Round 3
// 338.954 us; speedup vs baseline: 2.2207x; 2.2207x over previous
//
#include <hip/hip_runtime.h>

// CubicSplineUpsampling: (2,3,96,96,96) f32 -> (2,3,192,192,192) f32.
//
// out_line(192) = M * in_line(96) per axis, M = U_clamped(192x96) . W(96x96),
// banded to 28 taps at j0=(i>>1)-13 (truncation ~1e-8 relative).
// All passes use a 35-float sliding register window, 8-step unrolled chunks
// with explicit register shift (compile-time indices -> guaranteed VGPR
// residency; R2's x[96] spilled to scratch). Weights via readfirstlane ->
// s_load (scalar pipe). Z pass staged through padded LDS for coalescing.

#define TAPS 28
#define WIN 35

__device__ double g_Wd[96 * 96];
__device__ float g_Mb[192 * TAPS];            // [i][t] row-major
__device__ float g_bufA[6 * 96 * 96 * 192];   // after Z pass
__device__ float g_bufB[6 * 96 * 192 * 192];  // after Y pass

__device__ __forceinline__ int clamp96(int j) { return j < 0 ? 0 : (j > 95 ? 95 : j); }

__global__ void compute_Wd_kernel(double* __restrict__ Wd) {
    int j = threadIdx.x;
    if (j >= 96) return;
    const double p = -0.26794919243112270647253365849413;  // sqrt(3)-2
    double c[96];
    double pj = 1.0;
    for (int t = 0; t < j; ++t) pj *= p;
    double p191j = 1.0;
    for (int t = 0; t < 191 - j; ++t) p191j *= p;
    double p2n = 1.0;
    for (int t = 0; t < 192; ++t) p2n *= p;
    double K = p / (1.0 - p2n);
    double cur = 6.0 * K * (pj + p191j) + (j == 0 ? 6.0 : 0.0);
    c[0] = cur;
    for (int i = 1; i < 96; ++i) {
        cur = (i == j ? 6.0 : 0.0) + p * cur;
        c[i] = cur;
    }
    double nxt = cur * (p / (p - 1.0));
    Wd[95 * 96 + j] = nxt;
    for (int i = 94; i >= 0; --i) {
        nxt = p * (nxt - c[i]);
        Wd[i * 96 + j] = nxt;
    }
}

__global__ void compute_M_kernel(const double* __restrict__ Wd, float* __restrict__ Mb) {
    int i = threadIdx.x;
    if (i >= 192) return;
    const double cw[8] = {1.0 / 384.0, 121.0 / 384.0, 235.0 / 384.0, 27.0 / 384.0,
                          27.0 / 384.0, 235.0 / 384.0, 121.0 / 384.0, 1.0 / 384.0};
    int ph = i & 1;
    int c = i >> 1;
    for (int t = 0; t < TAPS; ++t) {
        int j = c - 13 + t;
        double m = 0.0;
        if (j >= 0 && j < 96) {
            for (int tt = 0; tt < 4; ++tt) {
                int k = c + ph - 2 + tt;
                k = k < 0 ? 0 : (k > 95 ? 95 : k);
                m += cw[ph * 4 + tt] * Wd[k * 96 + j];
            }
        }
        Mb[i * TAPS + t] = (float)m;
    }
}

// Z pass: lines contiguous along z. Block: 64 lines staged in padded LDS,
// wave w handles m in [24w, 24w+24); output tile staged, coalesced write.
__global__ __launch_bounds__(256) void pass_z(const float* __restrict__ in,
                                              float* __restrict__ out,
                                              const float* __restrict__ Mb) {
    __shared__ float s_in[64 * 97];
    __shared__ float s_out[64 * 193];
    size_t base = (size_t)blockIdx.x * 64;
    const float* src = in + base * 96;
    int tid = threadIdx.x;
    for (int k = tid; k < 64 * 96; k += 256)
        s_in[(k / 96) * 97 + (k % 96)] = src[k];
    __syncthreads();

    int lane = tid & 63;
    int wave = tid >> 6;
    int m0 = wave * 24;
    const float* xl = s_in + lane * 97;
    float* ol = s_out + lane * 193;
    float win[WIN];
#pragma unroll
    for (int k = 0; k < WIN; ++k) win[k] = xl[clamp96(m0 - 13 + k)];
    for (int ch = 0; ch < 3; ++ch) {
        int mc = m0 + ch * 8;
#pragma unroll
        for (int mi = 0; mi < 8; ++mi) {
            int m = mc + mi;
            int wb = __builtin_amdgcn_readfirstlane(m * 2 * TAPS);
            const float* wr = Mb + wb;
            float a0 = 0.f, a1 = 0.f;
#pragma unroll
            for (int t = 0; t < TAPS; ++t) {
                float xv = win[mi + t];
                a0 = fmaf(wr[t], xv, a0);
                a1 = fmaf(wr[TAPS + t], xv, a1);
            }
            ol[2 * m] = a0;
            ol[2 * m + 1] = a1;
        }
        if (ch < 2) {
#pragma unroll
            for (int k = 0; k < WIN - 8; ++k) win[k] = win[k + 8];
#pragma unroll
            for (int k = 0; k < 8; ++k) win[WIN - 8 + k] = xl[clamp96(mc + 22 + k)];
        }
    }
    __syncthreads();
    float* dst = out + base * 192;
    for (int k = tid; k < 64 * 192; k += 256)
        dst[k] = s_out[(k / 192) * 193 + (k % 192)];
}

// Y/X pass: [O][96][INNER] -> [O][192][INNER]. Thread = (o, segment, r);
// consecutive lanes -> consecutive r (INNER % 64 == 0) -> coalesced.
template <int INNER, int SEG>
__global__ __launch_bounds__(256) void pass_line(const float* __restrict__ in,
                                                 float* __restrict__ out,
                                                 const float* __restrict__ Mb) {
    constexpr int SPAN = 96 / SEG;
    constexpr int CHUNKS = SPAN / 8;
    int idx = blockIdx.x * 256 + threadIdx.x;
    int r = idx % INNER;
    int q = idx / INNER;
    int s = q % SEG;
    int o = q / SEG;
    const float* src = in + (size_t)o * 96 * INNER + r;
    float* dst = out + (size_t)o * 192 * INNER + r;
    int m0 = s * SPAN;
    float win[WIN];
#pragma unroll
    for (int k = 0; k < WIN; ++k) win[k] = src[(size_t)clamp96(m0 - 13 + k) * INNER];
    for (int ch = 0; ch < CHUNKS; ++ch) {
        int mc = m0 + ch * 8;
#pragma unroll
        for (int mi = 0; mi < 8; ++mi) {
            int m = mc + mi;
            int wb = __builtin_amdgcn_readfirstlane(m * 2 * TAPS);
            const float* wr = Mb + wb;
            float a0 = 0.f, a1 = 0.f;
#pragma unroll
            for (int t = 0; t < TAPS; ++t) {
                float xv = win[mi + t];
                a0 = fmaf(wr[t], xv, a0);
                a1 = fmaf(wr[TAPS + t], xv, a1);
            }
            dst[(size_t)(2 * m) * INNER] = a0;
            dst[(size_t)(2 * m + 1) * INNER] = a1;
        }
        if (ch < CHUNKS - 1) {
#pragma unroll
            for (int k = 0; k < WIN - 8; ++k) win[k] = win[k + 8];
#pragma unroll
            for (int k = 0; k < 8; ++k)
                win[WIN - 8 + k] = src[(size_t)clamp96(mc + 22 + k) * INNER];
        }
    }
}

extern "C" void kernel_launch(void* const* d_in, const int* in_sizes, int n_in,
                              void* d_out, int out_size, void* d_ws, size_t ws_size,
                              hipStream_t stream) {
    const float* x = (const float*)d_in[0];
    float* out = (float*)d_out;
    double* Wd;
    float *Mb, *bufA, *bufB;
    hipGetSymbolAddress((void**)&Wd, HIP_SYMBOL(g_Wd));
    hipGetSymbolAddress((void**)&Mb, HIP_SYMBOL(g_Mb));
    hipGetSymbolAddress((void**)&bufA, HIP_SYMBOL(g_bufA));
    hipGetSymbolAddress((void**)&bufB, HIP_SYMBOL(g_bufB));

    compute_Wd_kernel<<<1, 96, 0, stream>>>(Wd);
    compute_M_kernel<<<1, 192, 0, stream>>>(Wd, Mb);

    // Z: 6*96*96 = 55296 lines / 64 per block
    pass_z<<<864, 256, 0, stream>>>(x, bufA, Mb);
    // Y: O = 6*96 = 576, INNER = 192, SEG = 4 -> 576*4*192/256 = 1728 blocks
    pass_line<192, 4><<<1728, 256, 0, stream>>>(bufA, bufB, Mb);
    // X: O = 6, INNER = 192*192 = 36864, SEG = 2 -> 6*2*36864/256 = 1728 blocks
    pass_line<36864, 2><<<1728, 256, 0, stream>>>(bufB, out, Mb);
}